// Round 1
// baseline (757.297 us; speedup 1.0000x reference)
//
#include <hip/hip_runtime.h>
#include <cstddef>

// Problem constants (fixed by reference setup)
constexpr int Bb   = 32;
constexpr int Ss   = 1024;
constexpr int Dd   = 256;
constexpr int Ff   = 256;
constexpr int TMAX = 8192;
constexpr int MM   = Bb * Ss;          // 32768 rows
constexpr float LN_EPS = 1e-5f;

// ---------------------------------------------------------------------------
// Transpose conv weights [F][D][K] -> [K][D][F] so GEMM B-tile loads coalesce.
// ---------------------------------------------------------------------------
__global__ __launch_bounds__(256) void transpose_w_k(
    const float* __restrict__ w1, const float* __restrict__ w2,
    float* __restrict__ wT1, float* __restrict__ wT2)
{
    int i = blockIdx.x * 256 + threadIdx.x;     // 0 .. 2*196608-1
    const float* w = w1;
    float* o = wT1;
    int j = i;
    if (j >= 3 * Dd * Ff) { j -= 3 * Dd * Ff; w = w2; o = wT2; }
    int f = j & 255;
    int d = (j >> 8) & 255;
    int k = j >> 16;
    o[j] = w[(f * 256 + d) * 3 + k];
}

// ---------------------------------------------------------------------------
// conv1d as GEMM: out[m][f] = sum_{k,d} in[b][s+k-1][d] * wT[k][d][f] + bias[f]
// in: [B,S,256] (zero-padded at batch edges), wT: [3][256][256], out: [B,S,256]
// 64x64 tile, 256 threads, 4x4 accum per thread.
// ---------------------------------------------------------------------------
__global__ __launch_bounds__(256, 4) void conv_gemm(
    const float* __restrict__ in, const float* __restrict__ wT,
    const float* __restrict__ bias, float* __restrict__ out)
{
    __shared__ float At[64][68];   // [d][s], +4 pad keeps float4 reads 16B-aligned
    __shared__ float Bt[64][64];   // [d][f]

    const int bx = blockIdx.x & 3;        // f tile (F/64 = 4)
    const int my = blockIdx.x >> 2;       // m tile
    const int m0 = my * 64;
    const int b  = m0 >> 10;
    const int s0 = m0 & 1023;
    const int f0 = bx * 64;

    const int tid  = threadIdx.x;
    const int tx   = tid & 15;
    const int ty   = tid >> 4;
    const int lrow = tid >> 4;            // 0..15 (staging)
    const int lcol = (tid & 15) * 4;      // 0..60 (staging)

    float acc[4][4] = {};

    for (int k = 0; k < 3; ++k) {
        for (int d0 = 0; d0 < 256; d0 += 64) {
            // ---- stage A (transpose into LDS) ----
            #pragma unroll
            for (int p = 0; p < 4; ++p) {
                int sl = p * 16 + lrow;
                int sg = s0 + sl + k - 1;
                float4 v = make_float4(0.f, 0.f, 0.f, 0.f);
                if (sg >= 0 && sg < Ss)
                    v = *(const float4*)&in[((size_t)(b << 10) + sg) * 256 + d0 + lcol];
                At[lcol + 0][sl] = v.x;
                At[lcol + 1][sl] = v.y;
                At[lcol + 2][sl] = v.z;
                At[lcol + 3][sl] = v.w;
            }
            // ---- stage B ----
            #pragma unroll
            for (int p = 0; p < 4; ++p) {
                int dl = p * 16 + lrow;
                *(float4*)&Bt[dl][lcol] =
                    *(const float4*)&wT[(size_t)((k * 256 + d0 + dl) << 8) + f0 + lcol];
            }
            __syncthreads();
            // ---- compute ----
            #pragma unroll
            for (int d = 0; d < 64; ++d) {
                float4 a  = *(const float4*)&At[d][ty * 4];
                float4 bb = *(const float4*)&Bt[d][tx * 4];
                acc[0][0] += a.x * bb.x; acc[0][1] += a.x * bb.y;
                acc[0][2] += a.x * bb.z; acc[0][3] += a.x * bb.w;
                acc[1][0] += a.y * bb.x; acc[1][1] += a.y * bb.y;
                acc[1][2] += a.y * bb.z; acc[1][3] += a.y * bb.w;
                acc[2][0] += a.z * bb.x; acc[2][1] += a.z * bb.y;
                acc[2][2] += a.z * bb.z; acc[2][3] += a.z * bb.w;
                acc[3][0] += a.w * bb.x; acc[3][1] += a.w * bb.y;
                acc[3][2] += a.w * bb.z; acc[3][3] += a.w * bb.w;
            }
            __syncthreads();
        }
    }

    float4 bv = *(const float4*)&bias[f0 + tx * 4];
    #pragma unroll
    for (int i = 0; i < 4; ++i) {
        int m = m0 + ty * 4 + i;
        float4 o;
        o.x = acc[i][0] + bv.x;
        o.y = acc[i][1] + bv.y;
        o.z = acc[i][2] + bv.z;
        o.w = acc[i][3] + bv.w;
        *(float4*)&out[(size_t)m * 256 + f0 + tx * 4] = o;
    }
}

// ---------------------------------------------------------------------------
// ReLU + LayerNorm over last dim (256). One wave per row, 4 rows/block.
// ---------------------------------------------------------------------------
__global__ __launch_bounds__(256) void relu_ln(
    const float* __restrict__ in, float* __restrict__ out,
    const float* __restrict__ g, const float* __restrict__ bt)
{
    int row  = blockIdx.x * 4 + (threadIdx.x >> 6);
    int lane = threadIdx.x & 63;
    float4 v = ((const float4*)(in + (size_t)row * 256))[lane];
    v.x = fmaxf(v.x, 0.f); v.y = fmaxf(v.y, 0.f);
    v.z = fmaxf(v.z, 0.f); v.w = fmaxf(v.w, 0.f);
    float s = v.x + v.y + v.z + v.w;
    #pragma unroll
    for (int off = 32; off > 0; off >>= 1) s += __shfl_xor(s, off, 64);
    float mu = s * (1.f / 256.f);
    float4 dv = make_float4(v.x - mu, v.y - mu, v.z - mu, v.w - mu);
    float q = dv.x * dv.x + dv.y * dv.y + dv.z * dv.z + dv.w * dv.w;
    #pragma unroll
    for (int off = 32; off > 0; off >>= 1) q += __shfl_xor(q, off, 64);
    float r = rsqrtf(q * (1.f / 256.f) + LN_EPS);
    float4 g4 = ((const float4*)g)[lane];
    float4 b4 = ((const float4*)bt)[lane];
    float4 o;
    o.x = dv.x * r * g4.x + b4.x;
    o.y = dv.y * r * g4.y + b4.y;
    o.z = dv.z * r * g4.z + b4.z;
    o.w = dv.w * r * g4.w + b4.w;
    ((float4*)(out + (size_t)row * 256))[lane] = o;
}

// ---------------------------------------------------------------------------
// ReLU + LayerNorm + linear head -> log_dur[row] (with mask).
// ---------------------------------------------------------------------------
__global__ __launch_bounds__(256) void relu_ln_lin(
    const float* __restrict__ in, const float* __restrict__ g,
    const float* __restrict__ bt, const float* __restrict__ lw,
    const float* __restrict__ lb, const unsigned char* __restrict__ mask,
    float* __restrict__ out_logdur)
{
    int row  = blockIdx.x * 4 + (threadIdx.x >> 6);
    int lane = threadIdx.x & 63;
    float4 v = ((const float4*)(in + (size_t)row * 256))[lane];
    v.x = fmaxf(v.x, 0.f); v.y = fmaxf(v.y, 0.f);
    v.z = fmaxf(v.z, 0.f); v.w = fmaxf(v.w, 0.f);
    float s = v.x + v.y + v.z + v.w;
    #pragma unroll
    for (int off = 32; off > 0; off >>= 1) s += __shfl_xor(s, off, 64);
    float mu = s * (1.f / 256.f);
    float4 dv = make_float4(v.x - mu, v.y - mu, v.z - mu, v.w - mu);
    float q = dv.x * dv.x + dv.y * dv.y + dv.z * dv.z + dv.w * dv.w;
    #pragma unroll
    for (int off = 32; off > 0; off >>= 1) q += __shfl_xor(q, off, 64);
    float r = rsqrtf(q * (1.f / 256.f) + LN_EPS);
    float4 g4 = ((const float4*)g)[lane];
    float4 b4 = ((const float4*)bt)[lane];
    float4 o;
    o.x = dv.x * r * g4.x + b4.x;
    o.y = dv.y * r * g4.y + b4.y;
    o.z = dv.z * r * g4.z + b4.z;
    o.w = dv.w * r * g4.w + b4.w;
    float4 w4 = ((const float4*)lw)[lane];
    float p = o.x * w4.x + o.y * w4.y + o.z * w4.z + o.w * w4.w;
    #pragma unroll
    for (int off = 32; off > 0; off >>= 1) p += __shfl_xor(p, off, 64);
    if (lane == 0) {
        float ld = p + lb[0];
        if (mask[row]) ld = 0.f;   // mask is all-false in this problem; cheap safety
        out_logdur[row] = ld;
    }
}

// ---------------------------------------------------------------------------
// Per-batch inclusive cumsum of duration (S=1024), plus dur->float and mel_len.
// ---------------------------------------------------------------------------
__global__ __launch_bounds__(256) void cumsum_k(
    const int* __restrict__ dur, int* __restrict__ cum,
    float* __restrict__ dur_out, float* __restrict__ mel_out)
{
    int b = blockIdx.x, tid = threadIdx.x;
    int4 d4 = ((const int4*)(dur + b * 1024))[tid];
    int l0 = d4.x, l1 = l0 + d4.y, l2 = l1 + d4.z, l3 = l2 + d4.w;
    __shared__ int sc[256];
    sc[tid] = l3;
    __syncthreads();
    for (int off = 1; off < 256; off <<= 1) {
        int v = (tid >= off) ? sc[tid - off] : 0;
        __syncthreads();
        sc[tid] += v;
        __syncthreads();
    }
    int excl = sc[tid] - l3;
    ((int4*)(cum + b * 1024))[tid] = make_int4(excl + l0, excl + l1, excl + l2, excl + l3);
    ((float4*)(dur_out + b * 1024))[tid] =
        make_float4((float)d4.x, (float)d4.y, (float)d4.z, (float)d4.w);
    if (tid == 255) mel_out[b] = (float)min(excl + l3, TMAX);
}

// ---------------------------------------------------------------------------
// searchsorted(cum, t, 'right') per (b,t); -1 marks invalid (t >= mel_len).
// ---------------------------------------------------------------------------
__global__ __launch_bounds__(256) void searchsorted_k(
    const int* __restrict__ cum, int* __restrict__ idx)
{
    int b = blockIdx.x, tid = threadIdx.x;
    __shared__ int sc[1024];
    ((int4*)sc)[tid] = ((const int4*)(cum + b * 1024))[tid];
    __syncthreads();
    int mel = min(sc[1023], TMAX);
    for (int t = tid; t < TMAX; t += 256) {
        int lo = 0, hi = 1024;
        #pragma unroll
        for (int it = 0; it < 10; ++it) {
            int mid = (lo + hi) >> 1;
            if (sc[mid] <= t) lo = mid + 1; else hi = mid;
        }
        idx[b * TMAX + t] = (t < mel) ? min(lo, 1023) : -1;
    }
}

// ---------------------------------------------------------------------------
// Gather rows of x per src idx; zero invalid rows. float4 granularity.
// ---------------------------------------------------------------------------
__global__ __launch_bounds__(256) void gather_k(
    const float4* __restrict__ xv, const int* __restrict__ idx,
    float4* __restrict__ outv)
{
    int g   = blockIdx.x * 256 + threadIdx.x;   // 0 .. 16,777,215
    int row = g >> 6;                           // b*T + t
    int col = g & 63;
    int s = idx[row];
    float4 v = make_float4(0.f, 0.f, 0.f, 0.f);
    if (s >= 0) {
        int b = row >> 13;
        v = xv[((size_t)(b << 10) + s) * 64 + col];
    }
    outv[g] = v;
}

// ---------------------------------------------------------------------------
extern "C" void kernel_launch(void* const* d_in, const int* in_sizes, int n_in,
                              void* d_out, int out_size, void* d_ws, size_t ws_size,
                              hipStream_t stream)
{
    const float* x            = (const float*)d_in[0];
    const unsigned char* mask = (const unsigned char*)d_in[1];
    const int* duration       = (const int*)d_in[2];
    // d_in[3] = max_len (constant 8192, compiled in as TMAX)
    const float* w1  = (const float*)d_in[4];
    const float* b1  = (const float*)d_in[5];
    const float* g1  = (const float*)d_in[6];
    const float* be1 = (const float*)d_in[7];
    const float* w2  = (const float*)d_in[8];
    const float* b2  = (const float*)d_in[9];
    const float* g2  = (const float*)d_in[10];
    const float* be2 = (const float*)d_in[11];
    const float* lw  = (const float*)d_in[12];
    const float* lb  = (const float*)d_in[13];

    float* out         = (float*)d_out;
    float* out0        = out;                                  // [B,T,D]
    float* out_logdur  = out + (size_t)Bb * TMAX * Dd;         // [B,S]
    float* out_dur     = out_logdur + (size_t)Bb * Ss;         // [B,S] (as float)
    float* out_mel     = out_dur + (size_t)Bb * Ss;            // [B]

    float* ws   = (float*)d_ws;
    float* wT1  = ws;                                          // 196608
    float* wT2  = wT1 + 3 * Dd * Ff;                           // 196608
    float* bufA = wT2 + 3 * Dd * Ff;                           // 8,388,608
    float* bufB = bufA + (size_t)MM * Ff;                      // 8,388,608
    int*   cum  = (int*)(bufB + (size_t)MM * Ff);              // 32768
    int*   idx  = cum + Bb * Ss;                               // 262144

    transpose_w_k<<<1536, 256, 0, stream>>>(w1, w2, wT1, wT2);
    conv_gemm   <<<(MM / 64) * (Ff / 64), 256, 0, stream>>>(x, wT1, b1, bufA);
    relu_ln     <<<MM / 4, 256, 0, stream>>>(bufA, bufB, g1, be1);
    conv_gemm   <<<(MM / 64) * (Ff / 64), 256, 0, stream>>>(bufB, wT2, b2, bufA);
    relu_ln_lin <<<MM / 4, 256, 0, stream>>>(bufA, g2, be2, lw, lb, mask, out_logdur);
    cumsum_k    <<<Bb, 256, 0, stream>>>(duration, cum, out_dur, out_mel);
    searchsorted_k<<<Bb, 256, 0, stream>>>(cum, idx);
    gather_k    <<<(Bb * TMAX * Dd / 4) / 256, 256, 0, stream>>>(
                    (const float4*)x, idx, (float4*)out0);
}

// Round 2
// 438.240 us; speedup vs baseline: 1.7280x; 1.7280x over previous
//
#include <hip/hip_runtime.h>
#include <cstddef>

// Problem constants (fixed by reference setup)
constexpr int Bb   = 32;
constexpr int Ss   = 1024;
constexpr int Dd   = 256;
constexpr int Ff   = 256;
constexpr int TMAX = 8192;
constexpr int MM   = Bb * Ss;          // 32768 rows
constexpr int KK   = 768;              // 3*256 reduction dim
constexpr int SP   = 1026;             // padded seq len (zero row at 0 and 1025)
constexpr float LN_EPS = 1e-5f;

typedef __bf16 bf16x8 __attribute__((ext_vector_type(8)));
typedef __bf16 bf16x4 __attribute__((ext_vector_type(4)));
typedef float  f32x4  __attribute__((ext_vector_type(4)));

// ---------------------------------------------------------------------------
// Pack conv weights [F][D][K] fp32 -> [F][K*256+D] bf16 ("wTT"): B-operand of
// the GEMM, laid out so LDS staging needs no transpose (n-major, k contiguous).
// Handles both convs (grid = 2 * 196608 / 256 = 1536 blocks).
// ---------------------------------------------------------------------------
__global__ __launch_bounds__(256) void pack_w_k(
    const float* __restrict__ w1, const float* __restrict__ w2,
    __bf16* __restrict__ wTT1, __bf16* __restrict__ wTT2)
{
    int i = blockIdx.x * 256 + threadIdx.x;
    const float* w = w1;
    __bf16* o = wTT1;
    int j = i;
    if (j >= Ff * KK) { j -= Ff * KK; w = w2; o = wTT2; }
    int d  = j & 255;
    int fk = j >> 8;           // f*3 + k
    int f  = fk / 3;
    int k  = fk - f * 3;
    // output index: f*768 + k*256 + d  == j with this mapping? No: recompute.
    o[(size_t)f * KK + k * 256 + d] = (__bf16)w[((size_t)(f * 256 + d)) * 3 + k];
}

// ---------------------------------------------------------------------------
// Pack x fp32 [B,1024,256] -> bf16 [B,1026,256] with zero rows at j=0,1025.
// ---------------------------------------------------------------------------
__global__ __launch_bounds__(256) void pack_x_k(
    const float* __restrict__ x, __bf16* __restrict__ xp)
{
    int i = blockIdx.x * 256 + threadIdx.x;      // over 32*1026*256/4
    int e4  = i * 4;
    int row = e4 >> 8;                           // 0 .. 32831
    int d   = e4 & 255;
    int b   = row / SP;
    int j   = row - b * SP;
    bf16x4 o;
    if (j == 0 || j == SP - 1) {
        o = (bf16x4)(__bf16)0.f;
    } else {
        float4 v = *(const float4*)&x[(((size_t)(b << 10) + (j - 1)) << 8) + d];
        o[0] = (__bf16)v.x; o[1] = (__bf16)v.y;
        o[2] = (__bf16)v.z; o[3] = (__bf16)v.w;
    }
    *(bf16x4*)&xp[((size_t)row << 8) + d] = o;
}

// ---------------------------------------------------------------------------
// Zero the pad rows (j=0, j=1025) of xp2 (relu_ln_bf16 only writes j=1..1024).
// ---------------------------------------------------------------------------
__global__ __launch_bounds__(256) void zero_pads_k(__bf16* __restrict__ xp2)
{
    int e = blockIdx.x * 256 + threadIdx.x;      // 0 .. 16383
    int b = e >> 9;
    int r = (e >> 8) & 1;                        // 0 -> row 0, 1 -> row 1025
    int d = e & 255;
    xp2[(((size_t)b * SP) + r * (SP - 1)) * 256 + d] = (__bf16)0.f;
}

// ---------------------------------------------------------------------------
// bf16 MFMA GEMM for conv1d-as-GEMM:
//   C[m][n] = sum_kk A[m][kk] * Bw[n][kk] + bias[n]
//   A[m][k*256+d] = xp[b][s + k][d]   (padded, so no bounds checks)
//   Bw = wTT [256 n][768 kk]
// 128x128 tile, 4 waves, 64x64 per wave, 16x16x32 bf16 MFMA, BK=64.
// ---------------------------------------------------------------------------
constexpr int BK  = 64;
constexpr int PIT = 72;   // LDS pitch (bf16): 144 B rows -> conflict-free b128

__global__ __launch_bounds__(256, 2) void gemm_mfma(
    const __bf16* __restrict__ Ap,   // [32][1026][256]
    const __bf16* __restrict__ Bw,   // [256][768]
    const float* __restrict__ bias,  // [256]
    float* __restrict__ C)           // [32768][256]
{
    __shared__ __bf16 As[128 * PIT];
    __shared__ __bf16 Bs[128 * PIT];

    const int tid = threadIdx.x;
    const int bm  = blockIdx.x >> 1;
    const int bn  = blockIdx.x & 1;
    const int m0  = bm * 128;
    const int b   = m0 >> 10;
    const int s0  = m0 & 1023;
    const int n0  = bn * 128;

    const int wave = tid >> 6;
    const int lane = tid & 63;
    const int wm = (wave & 1) * 64;
    const int wn = (wave >> 1) * 64;
    const int lm = lane & 15;
    const int lk = lane >> 4;            // 0..3

    f32x4 acc[4][4] = {};                // [mi][ni]

    for (int step = 0; step < KK / BK; ++step) {
        const int kk0  = step * BK;
        const int kblk = kk0 >> 8;       // which conv tap (BK divides 256)
        const int d0   = kk0 & 255;

        // ---- stage A: 128 rows x 64 bf16 (128 B/row), 16 B per thread x4 ----
        const __bf16* aSrc = Ap + (((size_t)(b * SP + s0 + kblk)) << 8) + d0;
        #pragma unroll
        for (int i = 0; i < 4; ++i) {
            int c = i * 256 + tid;       // 0..1023
            int r = c >> 3, q = c & 7;
            *(bf16x8*)&As[r * PIT + q * 8] =
                *(const bf16x8*)&aSrc[((size_t)r << 8) + q * 8];
        }
        // ---- stage B ----
        const __bf16* bSrc = Bw + (size_t)n0 * KK + kk0;
        #pragma unroll
        for (int i = 0; i < 4; ++i) {
            int c = i * 256 + tid;
            int r = c >> 3, q = c & 7;
            *(bf16x8*)&Bs[r * PIT + q * 8] =
                *(const bf16x8*)&bSrc[(size_t)r * KK + q * 8];
        }
        __syncthreads();

        // ---- compute: 2 k-chunks of 32, 16 MFMAs each ----
        #pragma unroll
        for (int kc = 0; kc < 2; ++kc) {
            bf16x8 af[4], bfr[4];
            #pragma unroll
            for (int mi = 0; mi < 4; ++mi)
                af[mi] = *(const bf16x8*)&As[(wm + mi * 16 + lm) * PIT + kc * 32 + lk * 8];
            #pragma unroll
            for (int ni = 0; ni < 4; ++ni)
                bfr[ni] = *(const bf16x8*)&Bs[(wn + ni * 16 + lm) * PIT + kc * 32 + lk * 8];
            #pragma unroll
            for (int mi = 0; mi < 4; ++mi)
                #pragma unroll
                for (int ni = 0; ni < 4; ++ni)
                    acc[mi][ni] = __builtin_amdgcn_mfma_f32_16x16x32_bf16(
                        af[mi], bfr[ni], acc[mi][ni], 0, 0, 0);
        }
        __syncthreads();
    }

    // ---- epilogue: C/D layout col = lane&15, row = (lane>>4)*4 + reg ----
    #pragma unroll
    for (int ni = 0; ni < 4; ++ni) {
        int col = n0 + wn + ni * 16 + lm;
        float bv = bias[col];
        #pragma unroll
        for (int mi = 0; mi < 4; ++mi) {
            int rbase = m0 + wm + mi * 16 + lk * 4;
            #pragma unroll
            for (int r = 0; r < 4; ++r)
                C[((size_t)(rbase + r) << 8) + col] = acc[mi][ni][r] + bv;
        }
    }
}

// ---------------------------------------------------------------------------
// ReLU + LayerNorm, fp32 in -> bf16 out into padded buffer at row s+1.
// ---------------------------------------------------------------------------
__global__ __launch_bounds__(256) void relu_ln_bf16(
    const float* __restrict__ in, __bf16* __restrict__ xp2,
    const float* __restrict__ g, const float* __restrict__ bt)
{
    int row  = blockIdx.x * 4 + (threadIdx.x >> 6);
    int lane = threadIdx.x & 63;
    float4 v = ((const float4*)(in + ((size_t)row << 8)))[lane];
    v.x = fmaxf(v.x, 0.f); v.y = fmaxf(v.y, 0.f);
    v.z = fmaxf(v.z, 0.f); v.w = fmaxf(v.w, 0.f);
    float s = v.x + v.y + v.z + v.w;
    #pragma unroll
    for (int off = 32; off > 0; off >>= 1) s += __shfl_xor(s, off, 64);
    float mu = s * (1.f / 256.f);
    float4 dv = make_float4(v.x - mu, v.y - mu, v.z - mu, v.w - mu);
    float q = dv.x * dv.x + dv.y * dv.y + dv.z * dv.z + dv.w * dv.w;
    #pragma unroll
    for (int off = 32; off > 0; off >>= 1) q += __shfl_xor(q, off, 64);
    float r = rsqrtf(q * (1.f / 256.f) + LN_EPS);
    float4 g4 = ((const float4*)g)[lane];
    float4 b4 = ((const float4*)bt)[lane];
    bf16x4 o;
    o[0] = (__bf16)(dv.x * r * g4.x + b4.x);
    o[1] = (__bf16)(dv.y * r * g4.y + b4.y);
    o[2] = (__bf16)(dv.z * r * g4.z + b4.z);
    o[3] = (__bf16)(dv.w * r * g4.w + b4.w);
    int b  = row >> 10;
    int sr = row & 1023;
    ((bf16x4*)(xp2 + (((size_t)(b * SP + sr + 1)) << 8)))[lane] = o;
}

// ---------------------------------------------------------------------------
// ReLU + LayerNorm + linear head -> log_dur[row] (with mask).
// ---------------------------------------------------------------------------
__global__ __launch_bounds__(256) void relu_ln_lin(
    const float* __restrict__ in, const float* __restrict__ g,
    const float* __restrict__ bt, const float* __restrict__ lw,
    const float* __restrict__ lb, const unsigned char* __restrict__ mask,
    float* __restrict__ out_logdur)
{
    int row  = blockIdx.x * 4 + (threadIdx.x >> 6);
    int lane = threadIdx.x & 63;
    float4 v = ((const float4*)(in + ((size_t)row << 8)))[lane];
    v.x = fmaxf(v.x, 0.f); v.y = fmaxf(v.y, 0.f);
    v.z = fmaxf(v.z, 0.f); v.w = fmaxf(v.w, 0.f);
    float s = v.x + v.y + v.z + v.w;
    #pragma unroll
    for (int off = 32; off > 0; off >>= 1) s += __shfl_xor(s, off, 64);
    float mu = s * (1.f / 256.f);
    float4 dv = make_float4(v.x - mu, v.y - mu, v.z - mu, v.w - mu);
    float q = dv.x * dv.x + dv.y * dv.y + dv.z * dv.z + dv.w * dv.w;
    #pragma unroll
    for (int off = 32; off > 0; off >>= 1) q += __shfl_xor(q, off, 64);
    float r = rsqrtf(q * (1.f / 256.f) + LN_EPS);
    float4 g4 = ((const float4*)g)[lane];
    float4 b4 = ((const float4*)bt)[lane];
    float4 o;
    o.x = dv.x * r * g4.x + b4.x;
    o.y = dv.y * r * g4.y + b4.y;
    o.z = dv.z * r * g4.z + b4.z;
    o.w = dv.w * r * g4.w + b4.w;
    float4 w4 = ((const float4*)lw)[lane];
    float p = o.x * w4.x + o.y * w4.y + o.z * w4.z + o.w * w4.w;
    #pragma unroll
    for (int off = 32; off > 0; off >>= 1) p += __shfl_xor(p, off, 64);
    if (lane == 0) {
        float ld = p + lb[0];
        if (mask[row]) ld = 0.f;
        out_logdur[row] = ld;
    }
}

// ---------------------------------------------------------------------------
// Per-batch inclusive cumsum of duration (S=1024), plus dur->float and mel_len.
// ---------------------------------------------------------------------------
__global__ __launch_bounds__(256) void cumsum_k(
    const int* __restrict__ dur, int* __restrict__ cum,
    float* __restrict__ dur_out, float* __restrict__ mel_out)
{
    int b = blockIdx.x, tid = threadIdx.x;
    int4 d4 = ((const int4*)(dur + b * 1024))[tid];
    int l0 = d4.x, l1 = l0 + d4.y, l2 = l1 + d4.z, l3 = l2 + d4.w;
    __shared__ int sc[256];
    sc[tid] = l3;
    __syncthreads();
    for (int off = 1; off < 256; off <<= 1) {
        int v = (tid >= off) ? sc[tid - off] : 0;
        __syncthreads();
        sc[tid] += v;
        __syncthreads();
    }
    int excl = sc[tid] - l3;
    ((int4*)(cum + b * 1024))[tid] = make_int4(excl + l0, excl + l1, excl + l2, excl + l3);
    ((float4*)(dur_out + b * 1024))[tid] =
        make_float4((float)d4.x, (float)d4.y, (float)d4.z, (float)d4.w);
    if (tid == 255) mel_out[b] = (float)min(excl + l3, TMAX);
}

// ---------------------------------------------------------------------------
// searchsorted(cum, t, 'right') per (b,t); -1 marks invalid (t >= mel_len).
// ---------------------------------------------------------------------------
__global__ __launch_bounds__(256) void searchsorted_k(
    const int* __restrict__ cum, int* __restrict__ idx)
{
    int b = blockIdx.x, tid = threadIdx.x;
    __shared__ int sc[1024];
    ((int4*)sc)[tid] = ((const int4*)(cum + b * 1024))[tid];
    __syncthreads();
    int mel = min(sc[1023], TMAX);
    for (int t = tid; t < TMAX; t += 256) {
        int lo = 0, hi = 1024;
        #pragma unroll
        for (int it = 0; it < 10; ++it) {
            int mid = (lo + hi) >> 1;
            if (sc[mid] <= t) lo = mid + 1; else hi = mid;
        }
        idx[b * TMAX + t] = (t < mel) ? min(lo, 1023) : -1;
    }
}

// ---------------------------------------------------------------------------
// Gather rows of x per src idx; zero invalid rows. float4 granularity.
// ---------------------------------------------------------------------------
__global__ __launch_bounds__(256) void gather_k(
    const float4* __restrict__ xv, const int* __restrict__ idx,
    float4* __restrict__ outv)
{
    int g   = blockIdx.x * 256 + threadIdx.x;   // 0 .. 16,777,215
    int row = g >> 6;                           // b*T + t
    int col = g & 63;
    int s = idx[row];
    float4 v = make_float4(0.f, 0.f, 0.f, 0.f);
    if (s >= 0) {
        int b = row >> 13;
        v = xv[((size_t)(b << 10) + s) * 64 + col];
    }
    outv[g] = v;
}

// ---------------------------------------------------------------------------
extern "C" void kernel_launch(void* const* d_in, const int* in_sizes, int n_in,
                              void* d_out, int out_size, void* d_ws, size_t ws_size,
                              hipStream_t stream)
{
    const float* x            = (const float*)d_in[0];
    const unsigned char* mask = (const unsigned char*)d_in[1];
    const int* duration       = (const int*)d_in[2];
    const float* w1  = (const float*)d_in[4];
    const float* b1  = (const float*)d_in[5];
    const float* g1  = (const float*)d_in[6];
    const float* be1 = (const float*)d_in[7];
    const float* w2  = (const float*)d_in[8];
    const float* b2  = (const float*)d_in[9];
    const float* g2  = (const float*)d_in[10];
    const float* be2 = (const float*)d_in[11];
    const float* lw  = (const float*)d_in[12];
    const float* lb  = (const float*)d_in[13];

    float* out        = (float*)d_out;
    float* out0       = out;                                  // [B,T,D]
    float* out_logdur = out + (size_t)Bb * TMAX * Dd;         // [B,S]
    float* out_dur    = out_logdur + (size_t)Bb * Ss;         // [B,S]
    float* out_mel    = out_dur + (size_t)Bb * Ss;            // [B]

    char* ws = (char*)d_ws;
    __bf16* xp1  = (__bf16*)ws;                               // 32*1026*256
    __bf16* xp2  = xp1 + (size_t)Bb * SP * 256;
    __bf16* wTT1 = xp2 + (size_t)Bb * SP * 256;               // 256*768
    __bf16* wTT2 = wTT1 + (size_t)Ff * KK;
    float*  bufA = (float*)(wTT2 + (size_t)Ff * KK);          // 32768*256
    int*    cum  = (int*)(bufA + (size_t)MM * Ff);
    int*    idx  = cum + Bb * Ss;

    pack_w_k     <<<2 * Ff * KK / 256, 256, 0, stream>>>(w1, w2, wTT1, wTT2);
    pack_x_k     <<<Bb * SP * 256 / 1024, 256, 0, stream>>>(x, xp1);
    zero_pads_k  <<<Bb * 2 * 256 / 256, 256, 0, stream>>>(xp2);
    gemm_mfma    <<<(MM / 128) * (Ff / 128), 256, 0, stream>>>(xp1, wTT1, b1, bufA);
    relu_ln_bf16 <<<MM / 4, 256, 0, stream>>>(bufA, xp2, g1, be1);
    gemm_mfma    <<<(MM / 128) * (Ff / 128), 256, 0, stream>>>(xp2, wTT2, b2, bufA);
    relu_ln_lin  <<<MM / 4, 256, 0, stream>>>(bufA, g2, be2, lw, lb, mask, out_logdur);
    cumsum_k     <<<Bb, 256, 0, stream>>>(duration, cum, out_dur, out_mel);
    searchsorted_k<<<Bb, 256, 0, stream>>>(cum, idx);
    gather_k     <<<(Bb * TMAX * Dd / 4) / 256, 256, 0, stream>>>(
                     (const float4*)x, idx, (float4*)out0);
}

// Round 3
// 380.927 us; speedup vs baseline: 1.9880x; 1.1505x over previous
//
#include <hip/hip_runtime.h>
#include <cstddef>

// Problem constants (fixed by reference setup)
constexpr int Bb   = 32;
constexpr int Ss   = 1024;
constexpr int Dd   = 256;
constexpr int Ff   = 256;
constexpr int TMAX = 8192;
constexpr int MM   = Bb * Ss;          // 32768 rows
constexpr int KK   = 768;              // 3*256 reduction dim
constexpr int SP   = 1026;             // padded seq len (zero rows at 0, 1025)
constexpr float LN_EPS = 1e-5f;
constexpr int PIT  = 72;               // LDS pitch (bf16): 144 B rows

typedef __bf16 bf16x8 __attribute__((ext_vector_type(8)));
typedef __bf16 bf16x4 __attribute__((ext_vector_type(4)));
typedef float  f32x4  __attribute__((ext_vector_type(4)));

// ---------------------------------------------------------------------------
// Pack conv weights [F][D][K] fp32 -> [F][K*256+D] bf16: GEMM B-operand,
// n-major with k contiguous so LDS staging needs no transpose.
// ---------------------------------------------------------------------------
__global__ __launch_bounds__(256) void pack_w_k(
    const float* __restrict__ w1, const float* __restrict__ w2,
    __bf16* __restrict__ wTT1, __bf16* __restrict__ wTT2)
{
    int i = blockIdx.x * 256 + threadIdx.x;
    const float* w = w1;
    __bf16* o = wTT1;
    int j = i;
    if (j >= Ff * KK) { j -= Ff * KK; w = w2; o = wTT2; }
    int d  = j & 255;
    int fk = j >> 8;           // f*3 + k
    int f  = fk / 3;
    int k  = fk - f * 3;
    o[(size_t)f * KK + k * 256 + d] = (__bf16)w[((size_t)(f * 256 + d)) * 3 + k];
}

// ---------------------------------------------------------------------------
// Pack x fp32 [B,1024,256] -> bf16 [B,1026,256] with zero rows at j=0,1025,
// plus zero the pad rows of xp2 (tail blocks).
// ---------------------------------------------------------------------------
constexpr int NMAIN = Bb * SP * 64;    // bf16x4 chunks in xp1
constexpr int NPAD  = Bb * 2 * 64;     // pad chunks in xp2

__global__ __launch_bounds__(256) void pack_x_k(
    const float* __restrict__ x, __bf16* __restrict__ xp1,
    __bf16* __restrict__ xp2)
{
    int i = blockIdx.x * 256 + threadIdx.x;
    if (i >= NMAIN) {
        int j = i - NMAIN;
        if (j < NPAD) {
            int b = j >> 7;
            int r = (j >> 6) & 1;
            int d = (j & 63) * 4;
            *(bf16x4*)&xp2[((size_t)b * SP + (size_t)r * (SP - 1)) * 256 + d] =
                (bf16x4)(__bf16)0.f;
        }
        return;
    }
    int e4  = i * 4;
    int row = e4 >> 8;
    int d   = e4 & 255;
    int b   = row / SP;
    int j   = row - b * SP;
    bf16x4 o;
    if (j == 0 || j == SP - 1) {
        o = (bf16x4)(__bf16)0.f;
    } else {
        float4 v = *(const float4*)&x[(((size_t)(b << 10) + (j - 1)) << 8) + d];
        o[0] = (__bf16)v.x; o[1] = (__bf16)v.y;
        o[2] = (__bf16)v.z; o[3] = (__bf16)v.w;
    }
    *(bf16x4*)&xp1[((size_t)row << 8) + d] = o;
}

// ---------------------------------------------------------------------------
// Fused conv-as-GEMM + bias + ReLU + LayerNorm [+ linear head].
// Tile: BM=64 rows x BN=256 cols (full F) so each block owns complete rows.
// 4 waves, 64x64 per wave (wave w covers cols w*64..w*64+63, all 64 rows).
// MODE 0: writes LN output as bf16 into padded xp2 (input of conv2).
// MODE 1: writes log_dur = LN(out) @ lin_w + lin_b (masked) as fp32.
// ---------------------------------------------------------------------------
template<int MODE>
__global__ __launch_bounds__(256, 3) void gemm_fused(
    const __bf16* __restrict__ Ap,   // [32][1026][256] padded activations
    const __bf16* __restrict__ Bw,   // [256][768]
    const float* __restrict__ bias,
    const float* __restrict__ g, const float* __restrict__ bt,
    const float* __restrict__ lw, const float* __restrict__ lb,
    const unsigned char* __restrict__ mask,
    __bf16* __restrict__ outB, float* __restrict__ outF)
{
    __shared__ __bf16 As[64 * PIT];    // 9216 B
    __shared__ __bf16 Bs[256 * PIT];   // 36864 B

    const int tid  = threadIdx.x;
    const int m0   = blockIdx.x * 64;
    const int bb   = m0 >> 10;
    const int s0   = m0 & 1023;
    const int wave = tid >> 6;
    const int lane = tid & 63;
    const int wn   = wave * 64;
    const int lm   = lane & 15;
    const int lk   = lane >> 4;

    f32x4 acc[4][4] = {};              // [mi][ni]

    for (int step = 0; step < KK / 64; ++step) {
        const int kk0  = step * 64;
        const int kblk = kk0 >> 8;     // conv tap
        const int d0   = kk0 & 255;
        const __bf16* aSrc = Ap + (((size_t)(bb * SP + s0 + kblk)) << 8) + d0;
        #pragma unroll
        for (int i = 0; i < 2; ++i) {
            int c = i * 256 + tid, r = c >> 3, q = c & 7;
            *(bf16x8*)&As[r * PIT + q * 8] =
                *(const bf16x8*)&aSrc[((size_t)r << 8) + q * 8];
        }
        const __bf16* bSrc = Bw + kk0;
        #pragma unroll
        for (int i = 0; i < 8; ++i) {
            int c = i * 256 + tid, r = c >> 3, q = c & 7;
            *(bf16x8*)&Bs[r * PIT + q * 8] =
                *(const bf16x8*)&bSrc[(size_t)r * KK + q * 8];
        }
        __syncthreads();
        #pragma unroll
        for (int kc = 0; kc < 2; ++kc) {
            bf16x8 af[4], bfr[4];
            #pragma unroll
            for (int mi = 0; mi < 4; ++mi)
                af[mi] = *(const bf16x8*)&As[(mi * 16 + lm) * PIT + kc * 32 + lk * 8];
            #pragma unroll
            for (int ni = 0; ni < 4; ++ni)
                bfr[ni] = *(const bf16x8*)&Bs[(wn + ni * 16 + lm) * PIT + kc * 32 + lk * 8];
            #pragma unroll
            for (int mi = 0; mi < 4; ++mi)
                #pragma unroll
                for (int ni = 0; ni < 4; ++ni)
                    acc[mi][ni] = __builtin_amdgcn_mfma_f32_16x16x32_bf16(
                        af[mi], bfr[ni], acc[mi][ni], 0, 0, 0);
        }
        __syncthreads();
    }

    // ---- epilogue: bias + ReLU, then LN row stats ----
    // C/D layout: col = wn + ni*16 + lm, row = mi*16 + lk*4 + r
    float* scrS = (float*)As;          // [4 waves][64 rows]
    float* scrQ = scrS + 256;

    float s_[4][4] = {}, q_[4][4] = {};
    #pragma unroll
    for (int ni = 0; ni < 4; ++ni) {
        float bv = bias[wn + ni * 16 + lm];
        #pragma unroll
        for (int mi = 0; mi < 4; ++mi)
            #pragma unroll
            for (int r = 0; r < 4; ++r) {
                float h = fmaxf(acc[mi][ni][r] + bv, 0.f);
                acc[mi][ni][r] = h;
                s_[mi][r] += h;
                q_[mi][r] += h * h;
            }
    }
    #pragma unroll
    for (int off = 1; off < 16; off <<= 1)
        #pragma unroll
        for (int mi = 0; mi < 4; ++mi)
            #pragma unroll
            for (int r = 0; r < 4; ++r) {
                s_[mi][r] += __shfl_xor(s_[mi][r], off, 64);
                q_[mi][r] += __shfl_xor(q_[mi][r], off, 64);
            }
    if (lm == 0) {
        #pragma unroll
        for (int mi = 0; mi < 4; ++mi)
            #pragma unroll
            for (int r = 0; r < 4; ++r) {
                int row = mi * 16 + lk * 4 + r;
                scrS[wave * 64 + row] = s_[mi][r];
                scrQ[wave * 64 + row] = q_[mi][r];
            }
    }
    __syncthreads();

    float mu[4][4], rs[4][4];
    #pragma unroll
    for (int mi = 0; mi < 4; ++mi)
        #pragma unroll
        for (int r = 0; r < 4; ++r) {
            int row = mi * 16 + lk * 4 + r;
            float S = scrS[row] + scrS[64 + row] + scrS[128 + row] + scrS[192 + row];
            float Q = scrQ[row] + scrQ[64 + row] + scrQ[128 + row] + scrQ[192 + row];
            float m_ = S * (1.f / 256.f);
            float v_ = Q * (1.f / 256.f) - m_ * m_;
            mu[mi][r] = m_;
            rs[mi][r] = rsqrtf(v_ + LN_EPS);
        }

    if constexpr (MODE == 0) {
        size_t obase = ((size_t)(bb * SP + s0 + 1)) << 8;
        #pragma unroll
        for (int ni = 0; ni < 4; ++ni) {
            int col = wn + ni * 16 + lm;
            float gv = g[col], bv2 = bt[col];
            #pragma unroll
            for (int mi = 0; mi < 4; ++mi)
                #pragma unroll
                for (int r = 0; r < 4; ++r) {
                    int row = mi * 16 + lk * 4 + r;
                    float o = (acc[mi][ni][r] - mu[mi][r]) * rs[mi][r] * gv + bv2;
                    outB[obase + ((size_t)row << 8) + col] = (__bf16)o;
                }
        }
    } else {
        float p_[4][4] = {};
        #pragma unroll
        for (int ni = 0; ni < 4; ++ni) {
            int col = wn + ni * 16 + lm;
            float gv = g[col], bv2 = bt[col], wv = lw[col];
            #pragma unroll
            for (int mi = 0; mi < 4; ++mi)
                #pragma unroll
                for (int r = 0; r < 4; ++r) {
                    float o = (acc[mi][ni][r] - mu[mi][r]) * rs[mi][r] * gv + bv2;
                    p_[mi][r] += o * wv;
                }
        }
        #pragma unroll
        for (int off = 1; off < 16; off <<= 1)
            #pragma unroll
            for (int mi = 0; mi < 4; ++mi)
                #pragma unroll
                for (int r = 0; r < 4; ++r)
                    p_[mi][r] += __shfl_xor(p_[mi][r], off, 64);
        __syncthreads();   // everyone done reading scrS/scrQ
        if (lm == 0) {
            #pragma unroll
            for (int mi = 0; mi < 4; ++mi)
                #pragma unroll
                for (int r = 0; r < 4; ++r)
                    scrS[wave * 64 + (mi * 16 + lk * 4 + r)] = p_[mi][r];
        }
        __syncthreads();
        if (tid < 64) {
            int row = tid;
            float v = scrS[row] + scrS[64 + row] + scrS[128 + row] + scrS[192 + row]
                      + lb[0];
            if (mask[m0 + row]) v = 0.f;
            outF[m0 + row] = v;
        }
    }
}

// ---------------------------------------------------------------------------
// Per-batch cumsum + dur->float + mel_len + searchsorted, fused (cum in LDS).
// ---------------------------------------------------------------------------
__global__ __launch_bounds__(256) void cumsum_ss_k(
    const int* __restrict__ dur, float* __restrict__ dur_out,
    float* __restrict__ mel_out, int* __restrict__ idx)
{
    int b = blockIdx.x, tid = threadIdx.x;
    __shared__ int ic[1024];
    __shared__ int sc[256];
    int4 d4 = ((const int4*)(dur + b * 1024))[tid];
    int l0 = d4.x, l1 = l0 + d4.y, l2 = l1 + d4.z, l3 = l2 + d4.w;
    sc[tid] = l3;
    __syncthreads();
    for (int off = 1; off < 256; off <<= 1) {
        int v = (tid >= off) ? sc[tid - off] : 0;
        __syncthreads();
        sc[tid] += v;
        __syncthreads();
    }
    int excl = sc[tid] - l3;
    ((int4*)ic)[tid] = make_int4(excl + l0, excl + l1, excl + l2, excl + l3);
    ((float4*)(dur_out + b * 1024))[tid] =
        make_float4((float)d4.x, (float)d4.y, (float)d4.z, (float)d4.w);
    if (tid == 255) mel_out[b] = (float)min(excl + l3, TMAX);
    __syncthreads();
    int mel = min(ic[1023], TMAX);
    for (int t = tid; t < TMAX; t += 256) {
        int lo = 0, hi = 1024;
        #pragma unroll
        for (int it = 0; it < 10; ++it) {
            int mid = (lo + hi) >> 1;
            if (ic[mid] <= t) lo = mid + 1; else hi = mid;
        }
        idx[b * TMAX + t] = (t < mel) ? min(lo, 1023) : -1;
    }
}

// ---------------------------------------------------------------------------
// Gather rows of x per src idx; zero invalid rows. float4 granularity.
// ---------------------------------------------------------------------------
__global__ __launch_bounds__(256) void gather_k(
    const float4* __restrict__ xv, const int* __restrict__ idx,
    float4* __restrict__ outv)
{
    int g   = blockIdx.x * 256 + threadIdx.x;
    int row = g >> 6;                           // b*T + t
    int col = g & 63;
    int s = idx[row];
    float4 v = make_float4(0.f, 0.f, 0.f, 0.f);
    if (s >= 0) {
        int b = row >> 13;
        v = xv[((size_t)(b << 10) + s) * 64 + col];
    }
    outv[g] = v;
}

// ---------------------------------------------------------------------------
extern "C" void kernel_launch(void* const* d_in, const int* in_sizes, int n_in,
                              void* d_out, int out_size, void* d_ws, size_t ws_size,
                              hipStream_t stream)
{
    const float* x            = (const float*)d_in[0];
    const unsigned char* mask = (const unsigned char*)d_in[1];
    const int* duration       = (const int*)d_in[2];
    const float* w1  = (const float*)d_in[4];
    const float* b1  = (const float*)d_in[5];
    const float* g1  = (const float*)d_in[6];
    const float* be1 = (const float*)d_in[7];
    const float* w2  = (const float*)d_in[8];
    const float* b2  = (const float*)d_in[9];
    const float* g2  = (const float*)d_in[10];
    const float* be2 = (const float*)d_in[11];
    const float* lw  = (const float*)d_in[12];
    const float* lb  = (const float*)d_in[13];

    float* out        = (float*)d_out;
    float* out0       = out;                                  // [B,T,D]
    float* out_logdur = out + (size_t)Bb * TMAX * Dd;         // [B,S]
    float* out_dur    = out_logdur + (size_t)Bb * Ss;         // [B,S]
    float* out_mel    = out_dur + (size_t)Bb * Ss;            // [B]

    char* ws = (char*)d_ws;
    __bf16* xp1  = (__bf16*)ws;                               // 32*1026*256
    __bf16* xp2  = xp1 + (size_t)Bb * SP * 256;
    __bf16* wTT1 = xp2 + (size_t)Bb * SP * 256;               // 256*768
    __bf16* wTT2 = wTT1 + (size_t)Ff * KK;
    int*    idx  = (int*)(wTT2 + (size_t)Ff * KK);            // 32*8192

    pack_w_k   <<<2 * Ff * KK / 256, 256, 0, stream>>>(w1, w2, wTT1, wTT2);
    pack_x_k   <<<(NMAIN + NPAD) / 256, 256, 0, stream>>>(x, xp1, xp2);
    gemm_fused<0><<<MM / 64, 256, 0, stream>>>(
        xp1, wTT1, b1, g1, be1, nullptr, nullptr, nullptr, xp2, nullptr);
    gemm_fused<1><<<MM / 64, 256, 0, stream>>>(
        xp2, wTT2, b2, g2, be2, lw, lb, mask, nullptr, out_logdur);
    cumsum_ss_k<<<Bb, 256, 0, stream>>>(duration, out_dur, out_mel, idx);
    gather_k   <<<(Bb * TMAX * Dd / 4) / 256, 256, 0, stream>>>(
                   (const float4*)x, idx, (float4*)out0);
}